// Round 13
// baseline (370.125 us; speedup 1.0000x reference)
//
#include <hip/hip_runtime.h>
#include <hip/hip_bf16.h>

typedef __hip_bfloat16 bf16;
typedef __attribute__((ext_vector_type(8))) short short8;   // 8 bf16 = 4 VGPRs (MFMA A/B frag)
typedef __attribute__((ext_vector_type(4))) float f32x4;    // MFMA C/D frag

#define B_   8
#define S_   1024
#define D_   768
#define H_   12
#define HD_  64
#define MLP_ 3072
#define SD_  (S_ * D_)          // 786432 elements per batch

#define QSCALE 0.18033688011112042f   // log2(e) / 8  (softmax scale folded into q)

__device__ __forceinline__ float b2f(short h) {
  union { unsigned u; float f; } w;
  w.u = ((unsigned)(unsigned short)h) << 16;
  return w.f;
}

// single-instruction 2^x (v_exp_f32; ~1-2 ulp, fine under bf16 rounding)
__device__ __forceinline__ float fast_exp2(float x) {
  float r;
  asm("v_exp_f32 %0, %1" : "=v"(r) : "v"(x));
  return r;
}

// branch-free RNE float->bf16 (exact RNE for finite non-NaN inputs; 3 VALU)
__device__ __forceinline__ bf16 fastbf(float f) {
  union { float f; unsigned u; } w; w.f = f;
  unsigned r = (w.u + 0x7FFF + ((w.u >> 16) & 1)) >> 16;
  union { unsigned short s; bf16 b; } o; o.s = (unsigned short)r;
  return o.b;
}

// fp32 -> (bf16 RNE) -> fp32 (for colsum matching the MFMA's bf16 operands)
__device__ __forceinline__ float roundbf(float f) {
  union { float f; unsigned u; } w; w.f = f;
  w.u = ((w.u + 0x7FFF + ((w.u >> 16) & 1)) >> 16) << 16;
  return w.f;
}

// async global->LDS, 16B per lane; LDS dest must equal wave-uniform base + lane*16B
__device__ __forceinline__ void gl2lds16(const bf16* g, bf16* l) {
  __builtin_amdgcn_global_load_lds(
      (const __attribute__((address_space(1))) unsigned*)(const void*)g,
      (__attribute__((address_space(3))) unsigned*)(void*)l, 16, 0, 0);
}

// ---------------------------------------------------------------------------
// merged prep kernel (R12): one launch fills the machine with all prep work —
//   blocks [0,6912):      4 weight transposes (fp32 [R][C] -> bf16 [C][R])
//   blocks [6912,7680):   x-stats (atomicAdd raw sums -> red_x, pre-zeroed by
//                         hipMemsetAsync) + bf16 cast of x -> xb
//   blocks [7680,7692):   colsum(w1) -> cs1   — reads ORIGINAL fp32 weights,
//   blocks [7692,7701):   colsum(w_qkv) -> csq  rounded through bf16 (R9-
//                         verified numerics: absmax 0.03125) -> no dependency
//                         on the transposes -> stats run CONCURRENTLY.
// (R9 lesson kept: gemm EPI-0 reads precomputed TOTALS, never partials.)
// ---------------------------------------------------------------------------
__global__ __launch_bounds__(256) void prep_all(
    const float* __restrict__ w_qkv, const float* __restrict__ w_out,
    const float* __restrict__ w1, const float* __restrict__ w2,
    bf16* __restrict__ t_qkv, bf16* __restrict__ t_out,
    bf16* __restrict__ t1, bf16* __restrict__ t2,
    const float* __restrict__ x, bf16* __restrict__ xb,
    float* __restrict__ red_x, float* __restrict__ cs1,
    float* __restrict__ csq) {
  const int t = blockIdx.x;

  if (t >= 7680) {                              // colsum over K of ORIGINAL w
    const float* wsrc; float* cdst; int C, n0;
    if (t < 7692) { wsrc = w1;    cdst = cs1; C = 3072; n0 = (t - 7680) * 256; }
    else          { wsrc = w_qkv; cdst = csq; C = 2304; n0 = (t - 7692) * 256; }
    const int n = n0 + threadIdx.x;             // coalesced across threads
    float s = 0.f;
#pragma unroll 8
    for (int k = 0; k < 768; ++k)
      s += roundbf(wsrc[(long)k * C + n]);
    cdst[n] = s;
    return;
  }

  if (t >= 6912) {                              // x-stats + bf16 cast
    const int bi = t - 6912;
    const long off = (long)bi * 8192;
    float s = 0.f, s2 = 0.f;
#pragma unroll
    for (int it = 0; it < 4; ++it) {
      const long i = off + ((long)threadIdx.x + it * 256) * 8;
      float4 v0 = *(const float4*)(x + i);
      float4 v1 = *(const float4*)(x + i + 4);
      s += v0.x + v0.y + v0.z + v0.w + v1.x + v1.y + v1.z + v1.w;
      s2 += v0.x * v0.x + v0.y * v0.y + v0.z * v0.z + v0.w * v0.w +
            v1.x * v1.x + v1.y * v1.y + v1.z * v1.z + v1.w * v1.w;
      __align__(16) bf16 tmp[8];
      tmp[0] = __float2bfloat16(v0.x); tmp[1] = __float2bfloat16(v0.y);
      tmp[2] = __float2bfloat16(v0.z); tmp[3] = __float2bfloat16(v0.w);
      tmp[4] = __float2bfloat16(v1.x); tmp[5] = __float2bfloat16(v1.y);
      tmp[6] = __float2bfloat16(v1.z); tmp[7] = __float2bfloat16(v1.w);
      *(short8*)(xb + i) = *(const short8*)tmp;
    }
#pragma unroll
    for (int o = 1; o < 64; o <<= 1) { s += __shfl_xor(s, o, 64); s2 += __shfl_xor(s2, o, 64); }
    __shared__ float sh[8];
    const int wave = threadIdx.x >> 6, lane = threadIdx.x & 63;
    if (lane == 0) { sh[wave * 2] = s; sh[wave * 2 + 1] = s2; }
    __syncthreads();
    if (threadIdx.x == 0) {
      const int bb = bi / 96;                   // 96 blocks per batch
      atomicAdd(&red_x[bb * 2],     sh[0] + sh[2] + sh[4] + sh[6]);
      atomicAdd(&red_x[bb * 2 + 1], sh[1] + sh[3] + sh[5] + sh[7]);
    }
    return;
  }

  const float* in; bf16* out; int R, C, idx;
  if (t < 1728)      { in = w_qkv; out = t_qkv; R = 768;  C = 2304; idx = t; }
  else if (t < 2304) { in = w_out; out = t_out; R = 768;  C = 768;  idx = t - 1728; }
  else if (t < 4608) { in = w1;    out = t1;    R = 768;  C = 3072; idx = t - 2304; }
  else               { in = w2;    out = t2;    R = 3072; C = 768;  idx = t - 4608; }
  const int nbx = C >> 5;
  const int bx = (idx % nbx) * 32, by = (idx / nbx) * 32;
  __shared__ float tt[32][33];
  const int tx = threadIdx.x & 31, ty = threadIdx.x >> 5;  // ty: 0..7
#pragma unroll
  for (int rr = 0; rr < 32; rr += 8)
    tt[ty + rr][tx] = in[(long)(by + ty + rr) * C + bx + tx];
  __syncthreads();
#pragma unroll
  for (int rr = 0; rr < 32; rr += 8)
    out[(long)(bx + ty + rr) * R + by + tx] = __float2bfloat16(tt[tx][ty + rr]);
}

// ---------------------------------------------------------------------------
// MFMA GEMM: m97-exact structure (R3-measured best). TM=TN=128, BK=64,
// 4 waves (64x64/wave, acc[4][4]), SINGLE-buffered 32 KB LDS -> 3 blocks/CU.
// Two barriers per K-step; cross-block wave overlap hides the vmcnt drain.
// R0/R4/R5: dbuf, 8-wave, and 2-wave variants all regress.
// R9: inline stat-partial reduction in EPI-0 cost +8-10 µs.
// R10: setprio on MFMA clusters is null-to-harmful (barrier-locked waves).
// XOR 16B-chunk swizzle on both tiles.
// EPI 0: IN folded as affine (v = rs*(acc - mu*cs[n])), then QKV scatter
// EPI 1: v = acc+bias+res; outf fp32, outb0 bf16 copy (+ fused IN-stats)
// EPI 2: v = rs*(acc - mu*cs[n]) + bias (IN folded); gelu; outb0 bf16
// EPI 3: v = acc+bias+res; outf fp32 only
// ---------------------------------------------------------------------------
template <int EPI, bool STATS>
__global__ __launch_bounds__(256) void gemm_k(
    const bf16* __restrict__ A, const bf16* __restrict__ Bt,
    int M, int N, int K,
    const float* __restrict__ biasf, const float* __restrict__ resf,
    const float* __restrict__ cs, const float* __restrict__ stat_in,
    float* __restrict__ outf,
    bf16* __restrict__ outb0, bf16* __restrict__ outb1, bf16* __restrict__ outb2,
    float* __restrict__ statp) {
  __shared__ __align__(16) bf16 As[128 * 64];
  __shared__ __align__(16) bf16 Bs[128 * 64];
  __shared__ float sred[8];
  const int tid = threadIdx.x;
  const int bm = blockIdx.x * 128, bn = blockIdx.y * 128;
  const int wave = tid >> 6, lane = tid & 63;
  const int quad = lane >> 4, l16 = lane & 15;
  const int wm = (wave >> 1) * 64, wn = (wave & 1) * 64;
  const int swz = l16 & 7;            // row&7 for all fragment rows

  f32x4 acc[4][4];
#pragma unroll
  for (int i = 0; i < 4; ++i)
#pragma unroll
    for (int j = 0; j < 4; ++j) acc[i][j] = (f32x4){0.f, 0.f, 0.f, 0.f};

  const int srow = tid >> 3;                 // 0..31
  const int sgc = (tid & 7) ^ (srow & 7);    // swizzled global chunk for this LDS slot
  const bf16* Ab = A + (long)(bm + srow) * K + sgc * 8;
  const bf16* Bb = Bt + (long)(bn + srow) * K + sgc * 8;

  auto stage = [&](int k0) {
#pragma unroll
    for (int s = 0; s < 4; ++s)
      gl2lds16(Ab + (long)(s * 32) * K + k0, &As[0] + s * 2048 + tid * 8);
#pragma unroll
    for (int s = 0; s < 4; ++s)
      gl2lds16(Bb + (long)(s * 32) * K + k0, &Bs[0] + s * 2048 + tid * 8);
  };

  stage(0);
  const int nk = K >> 6;
  for (int kt = 0; kt < nk; ++kt) {
    __syncthreads();                  // stage(kt) landed (per-wave vmcnt drain)
    short8 a[2][4], b[2][4];
#pragma unroll
    for (int kk = 0; kk < 2; ++kk) {
      const int co = ((kk * 4 + quad) ^ swz) * 8;
#pragma unroll
      for (int i = 0; i < 4; ++i)
        a[kk][i] = *(const short8*)(&As[0] + (wm + i * 16 + l16) * 64 + co);
#pragma unroll
      for (int j = 0; j < 4; ++j)
        b[kk][j] = *(const short8*)(&Bs[0] + (wn + j * 16 + l16) * 64 + co);
    }
    __syncthreads();                  // all waves done reading; buffer free
    if (kt + 1 < nk) stage((kt + 1) * 64);
#pragma unroll
    for (int kk = 0; kk < 2; ++kk)
#pragma unroll
      for (int i = 0; i < 4; ++i)
#pragma unroll
        for (int j = 0; j < 4; ++j)
          acc[i][j] = __builtin_amdgcn_mfma_f32_16x16x32_bf16(a[kk][i], b[kk][j], acc[i][j], 0, 0, 0);
  }

  // epilogue: D[m][n] at m = quad*4+reg (+16*i), n = l16 (+16*j)
  const int m0 = bm + wm + quad * 4;
  const int n0 = bn + wn + l16;
  const int batch = bm >> 10;         // 128-row tile always within one batch
  float mu = 0.f, rs = 0.f;
  if (EPI == 0 || EPI == 2) {
    const float s1 = stat_in[batch * 2], s2v = stat_in[batch * 2 + 1];
    mu = s1 * (1.0f / SD_);
    rs = rsqrtf(s2v * (1.0f / SD_) - mu * mu + 1e-5f);
  }
  float ts = 0.f, ts2 = 0.f;
#pragma unroll
  for (int i = 0; i < 4; ++i) {
#pragma unroll
    for (int j = 0; j < 4; ++j) {
      const int n = n0 + j * 16;
#pragma unroll
      for (int r = 0; r < 4; ++r) {
        const int m = m0 + i * 16 + r;
        float v = acc[i][j][r];
        if (EPI == 0) {
          v = rs * (v - mu * cs[n]);    // instance-norm-1 folded (A was raw x)
          const int t = n / D_;
          const int rr2 = n - t * D_;
          const int hh = rr2 >> 6, dd = rr2 & 63;
          const int bb = m >> 10, ss = m & 1023;
          const long hoff = (long)(bb * H_ + hh);
          if (t == 0)      outb0[(hoff * S_ + ss) * HD_ + dd] = __float2bfloat16(v * QSCALE);
          else if (t == 1) outb1[(hoff * S_ + ss) * HD_ + dd] = __float2bfloat16(v);
          else             outb2[(hoff * HD_ + dd) * S_ + ss] = __float2bfloat16(v);
        } else if (EPI == 1) {
          v += biasf[n] + resf[(long)m * N + n];
          outf[(long)m * N + n] = v;
          outb0[(long)m * N + n] = __float2bfloat16(v);
          if (STATS) { ts += v; ts2 += v * v; }
        } else if (EPI == 2) {
          v = rs * (v - mu * cs[n]) + biasf[n];
          // tanh-form GELU via sigmoid: v * sigm(1.59577(v + 0.044715 v^3))
          float u = v * v;
          float y = v * (1.0f + 0.044715f * u) * 0.7978845608028654f;
          float z = fast_exp2(y * -2.885390081777927f);    // e^{-2y}
          v = v * __builtin_amdgcn_rcpf(1.0f + z);
          outb0[(long)m * N + n] = __float2bfloat16(v);
        } else {
          v += biasf[n] + resf[(long)m * N + n];
          outf[(long)m * N + n] = v;
        }
      }
    }
  }
  if (STATS) {                        // fused instance-norm partial sums
#pragma unroll
    for (int o = 1; o < 64; o <<= 1) { ts += __shfl_xor(ts, o, 64); ts2 += __shfl_xor(ts2, o, 64); }
    if (lane == 0) { sred[wave * 2] = ts; sred[wave * 2 + 1] = ts2; }
    __syncthreads();
    if (tid == 0) {
      atomicAdd(&statp[batch * 2], sred[0] + sred[2] + sred[4] + sred[6]);
      atomicAdd(&statp[batch * 2 + 1], sred[1] + sred[3] + sred[5] + sred[7]);
    }
  }
}

// ---------------------------------------------------------------------------
// flash attention: 4 waves x 64 q-rows per block, grid (B*H, S/64).
// (R11-measured best total.) In-reg P (R6), issue-early prefetch + fast_exp2
// + fastbf (R7). No setprio (R10 A/B: harmful).
// V B-fragment = two 8B runs/lane (kv 32kk+4q, 32kk+16+4q) -> 2x ds_read_b64.
// K/V LDS dbuf + XOR chunk swizzle; no-max softmax (q pre-scaled).
// ---------------------------------------------------------------------------
__global__ __launch_bounds__(256) void attn64(const bf16* __restrict__ q,
                                              const bf16* __restrict__ k,
                                              const bf16* __restrict__ vt,
                                              bf16* __restrict__ o) {
  __shared__ __align__(16) bf16 Ks[2][64 * 64];
  __shared__ __align__(16) bf16 Vs[2][64 * 64];   // [d][kv]
  const int bh = blockIdx.x, qt = blockIdx.y;
  const int tid = threadIdx.x, wave = tid >> 6, lane = tid & 63;
  const int quad = lane >> 4, l16 = lane & 15;
  const int sw = (l16 & 7) ^ ((l16 >> 3) & 1);   // swz(row) for rows ≡ l16 (mod 16)
  const long base = (long)bh * (S_ * HD_);
  const bf16* kg = k + base;
  const bf16* vg = vt + base;

  const int srow = tid >> 3;                                    // 0..31
  const int scg = (tid & 7) ^ (srow & 7) ^ ((srow >> 3) & 1);   // global chunk to fetch

  short8 aq[2];
#pragma unroll
  for (int kk = 0; kk < 2; ++kk)
    aq[kk] = *(const short8*)(q + base + (long)(qt * 64 + wave * 16 + l16) * HD_ +
                              kk * 32 + quad * 8);

  // stage tile 0 (256 lanes x 16B x 2 calls = full 8KB tile per buffer)
  gl2lds16(kg + (long)srow * HD_ + scg * 8, &Ks[0][0] + tid * 8);
  gl2lds16(kg + (long)(32 + srow) * HD_ + scg * 8, &Ks[0][0] + 2048 + tid * 8);
  gl2lds16(vg + (long)srow * S_ + scg * 8, &Vs[0][0] + tid * 8);
  gl2lds16(vg + (long)(32 + srow) * S_ + scg * 8, &Vs[0][0] + 2048 + tid * 8);

  // running next-tile prefetch pointers (K advances 64 rows, V advances 64 kv)
  const bf16* kp = kg + (long)(64 + srow) * HD_ + scg * 8;
  const bf16* vp = vg + (long)srow * S_ + 64 + scg * 8;

  f32x4 oacc[4];
#pragma unroll
  for (int j = 0; j < 4; ++j) oacc[j] = (f32x4){0.f, 0.f, 0.f, 0.f};
  float lp = 0.f;                       // per-lane partial sum for q-row l16

  // V b64 half-chunk offsets (bf16 elements), fixed per lane:
  //   chunk g = 4*kk + (quad>>1) (+2 for the hi run), half = quad&1
  const int vh = (quad & 1) * 4;

#define ATTN_STEP(CUR, DOPREF)                                                 \
  {                                                                            \
    __syncthreads();                                                           \
    if (DOPREF) {          /* issue-early: full step covers the latency */     \
      gl2lds16(kp, &Ks[(CUR) ^ 1][0] + tid * 8);                               \
      gl2lds16(kp + 32 * HD_, &Ks[(CUR) ^ 1][0] + 2048 + tid * 8);             \
      gl2lds16(vp, &Vs[(CUR) ^ 1][0] + tid * 8);                               \
      gl2lds16(vp + 32 * (long)S_, &Vs[(CUR) ^ 1][0] + 2048 + tid * 8);        \
      kp += 64 * HD_;                                                          \
      vp += 64;                                                                \
    }                                                                          \
    f32x4 s[4];                                                                \
    _Pragma("unroll")                                                          \
    for (int i = 0; i < 4; ++i) s[i] = (f32x4){0.f, 0.f, 0.f, 0.f};            \
    _Pragma("unroll")                                                          \
    for (int kk = 0; kk < 2; ++kk) {                                           \
      _Pragma("unroll")                                                        \
      for (int i = 0; i < 4; ++i) {                                            \
        short8 ak = *(const short8*)(&Ks[CUR][0] + (i * 16 + l16) * 64 +       \
                                     (((kk * 4 + quad) ^ sw) * 8));            \
        s[i] = __builtin_amdgcn_mfma_f32_16x16x32_bf16(ak, aq[kk], s[i], 0, 0, 0); \
      }                                                                        \
    }                                                                          \
    float pe[4][4];                                                            \
    _Pragma("unroll")                                                          \
    for (int i = 0; i < 4; ++i) {                                              \
      _Pragma("unroll")                                                        \
      for (int r = 0; r < 4; ++r) { pe[i][r] = fast_exp2(s[i][r]); lp += pe[i][r]; } \
    }                                                                          \
    union { short8 v; bf16 b[8]; } af[2];                                      \
    _Pragma("unroll")                                                          \
    for (int r = 0; r < 4; ++r) {                                              \
      af[0].b[r]     = fastbf(pe[0][r]);                                       \
      af[0].b[4 + r] = fastbf(pe[1][r]);                                       \
      af[1].b[r]     = fastbf(pe[2][r]);                                       \
      af[1].b[4 + r] = fastbf(pe[3][r]);                                       \
    }                                                                          \
    _Pragma("unroll")                                                          \
    for (int kk = 0; kk < 2; ++kk) {                                           \
      const int g0 = ((4 * kk + (quad >> 1)) ^ sw) * 8 + vh;                   \
      const int g1 = ((4 * kk + 2 + (quad >> 1)) ^ sw) * 8 + vh;               \
      _Pragma("unroll")                                                        \
      for (int dj = 0; dj < 4; ++dj) {                                         \
        const bf16* vrow = &Vs[CUR][0] + (dj * 16 + l16) * 64;                 \
        union { short8 v; uint2 u[2]; } bv;                                    \
        bv.u[0] = *(const uint2*)(vrow + g0);                                  \
        bv.u[1] = *(const uint2*)(vrow + g1);                                  \
        oacc[dj] = __builtin_amdgcn_mfma_f32_16x16x32_bf16(af[kk].v, bv.v, oacc[dj], 0, 0, 0); \
      }                                                                        \
    }                                                                          \
  }

  for (int c = 0; c < 16; c += 2) {
    ATTN_STEP(0, true)
    ATTN_STEP(1, (c < 14))
  }
#undef ATTN_STEP

  // reduce row sums: lane's lp covers quad's 16-kv slices; sum across quads
  float lt = lp;
  lt += __shfl_xor(lt, 16, 64);
  lt += __shfl_xor(lt, 32, 64);       // lane now holds full sum for q-row l16

  const int b = bh / H_, hh = bh - b * H_;
#pragma unroll
  for (int r = 0; r < 4; ++r) {
    const float inv = 1.0f / __shfl(lt, quad * 4 + r, 64);
    const int sg = qt * 64 + wave * 16 + quad * 4 + r;
    const long rowoff = ((long)b * S_ + sg) * D_ + hh * HD_;
#pragma unroll
    for (int dj = 0; dj < 4; ++dj)
      o[rowoff + dj * 16 + l16] = __float2bfloat16(oacc[dj][r] * inv);
  }
}

// ---------------------------------------------------------------------------
extern "C" void kernel_launch(void* const* d_in, const int* in_sizes, int n_in,
                              void* d_out, int out_size, void* d_ws, size_t ws_size,
                              hipStream_t stream) {
  const float* x     = (const float*)d_in[0];
  const float* w_qkv = (const float*)d_in[1];
  const float* w_out = (const float*)d_in[2];
  const float* b_out = (const float*)d_in[3];
  const float* w1    = (const float*)d_in[4];
  const float* b1    = (const float*)d_in[5];
  const float* w2    = (const float*)d_in[6];
  const float* b2    = (const float*)d_in[7];
  float* out = (float*)d_out;

  // workspace layout
  bf16* wt_qkv = (bf16*)d_ws;                 // [2304][768]
  bf16* wt_out = wt_qkv + 2304 * 768;         // [768][768]
  bf16* wt1    = wt_out + 768 * 768;          // [3072][768]
  bf16* wt2    = wt1 + 3072 * 768;            // [768][3072]
  bf16* qb     = wt2 + 768 * 3072;            // [B,H,S,HD] = 6291456
  bf16* kb     = qb + 6291456;
  bf16* vtb    = kb + 6291456;                // [B,H,HD,S]
  bf16* ob     = vtb + 6291456;               // attention out [B,S,D] bf16
  float* x1f   = (float*)(ob + 6291456);      // residual-1 fp32 [B,S,D]
  bf16* hb     = (bf16*)(x1f + 6291456);      // xb (bf16 x); later reused as x1b
  float* redp  = (float*)(hb + 6291456);      // (unused slot, kept for layout)
  float* red_x = redp + 1536;                 // 16 raw sums (norm-1, atomics)
  float* red2  = red_x + 16;                  // 16 raw sums (norm-2, atomics)
  float* cs1   = red2 + 16;                   // colsum(w1)[3072]
  float* csq   = cs1 + 3072;                  // colsum(w_qkv)[2304]
  bf16* gb     = qb;                          // MLP hidden reuses qb..ob (dead)
  bf16* xb     = hb;                          // bf16 cast of x
  bf16* x1b    = hb;                          // bf16 copy of x1 (xb dead after QKV)

  // 0. zero the 32 stat accumulators (red_x[16] + red2[16], contiguous)
  hipMemsetAsync(red_x, 0, 32 * sizeof(float), stream);

  // 1. merged prep: transposes + x-stats (atomic) + colsums-from-original
  prep_all<<<7701, 256, 0, stream>>>(w_qkv, w_out, w1, w2,
                                     wt_qkv, wt_out, wt1, wt2,
                                     x, xb, red_x, cs1, csq);

  // 2. QKV projection on RAW xb; instance-norm-1 folded into epilogue; scatter
  gemm_k<0, false><<<dim3(64, 18), 256, 0, stream>>>(
      xb, wt_qkv, 8192, 2304, 768, nullptr, nullptr, csq, red_x,
      nullptr, qb, kb, vtb, nullptr);
  // 3. attention (head-major grid; 4 waves x 64 q-rows)
  attn64<<<dim3(B_ * H_, 16), 256, 0, stream>>>(qb, kb, vtb, ob);

  // 4. out-projection + bias + residual -> x1f fp32 + x1b bf16, stats -> red2
  gemm_k<1, true><<<dim3(64, 6), 256, 0, stream>>>(
      ob, wt_out, 8192, 768, 768, b_out, x, nullptr, nullptr,
      x1f, x1b, nullptr, nullptr, red2);

  // 5. MLP up on UNNORMALIZED x1b; instance-norm-2 folded; tanh-GELU -> gb
  gemm_k<2, false><<<dim3(64, 24), 256, 0, stream>>>(
      x1b, wt1, 8192, 3072, 768, b1, nullptr, cs1, red2,
      nullptr, gb, nullptr, nullptr, nullptr);

  // 6. MLP down + bias + residual -> out
  gemm_k<3, false><<<dim3(64, 6), 256, 0, stream>>>(
      gb, wt2, 8192, 768, 3072, b2, x1f, nullptr, nullptr,
      out, nullptr, nullptr, nullptr, nullptr);
}

// Round 14
// 334.525 us; speedup vs baseline: 1.1064x; 1.1064x over previous
//
#include <hip/hip_runtime.h>
#include <hip/hip_bf16.h>

typedef __hip_bfloat16 bf16;
typedef __attribute__((ext_vector_type(8))) short short8;   // 8 bf16 = 4 VGPRs (MFMA A/B frag)
typedef __attribute__((ext_vector_type(4))) float f32x4;    // MFMA C/D frag

#define B_   8
#define S_   1024
#define D_   768
#define H_   12
#define HD_  64
#define MLP_ 3072
#define SD_  (S_ * D_)          // 786432 elements per batch

#define QSCALE 0.18033688011112042f   // log2(e) / 8  (softmax scale folded into q)

__device__ __forceinline__ float b2f(short h) {
  union { unsigned u; float f; } w;
  w.u = ((unsigned)(unsigned short)h) << 16;
  return w.f;
}

// single-instruction 2^x (v_exp_f32; ~1-2 ulp, fine under bf16 rounding)
__device__ __forceinline__ float fast_exp2(float x) {
  float r;
  asm("v_exp_f32 %0, %1" : "=v"(r) : "v"(x));
  return r;
}

// branch-free RNE float->bf16 (exact RNE for finite non-NaN inputs; 3 VALU)
__device__ __forceinline__ bf16 fastbf(float f) {
  union { float f; unsigned u; } w; w.f = f;
  unsigned r = (w.u + 0x7FFF + ((w.u >> 16) & 1)) >> 16;
  union { unsigned short s; bf16 b; } o; o.s = (unsigned short)r;
  return o.b;
}

// async global->LDS, 16B per lane; LDS dest must equal wave-uniform base + lane*16B
__device__ __forceinline__ void gl2lds16(const bf16* g, bf16* l) {
  __builtin_amdgcn_global_load_lds(
      (const __attribute__((address_space(1))) unsigned*)(const void*)g,
      (__attribute__((address_space(3))) unsigned*)(void*)l, 16, 0, 0);
}

// ---------------------------------------------------------------------------
// all 4 weight transposes (fp32 [R][C] -> bf16 [C][R]) in one launch.
// R13: 64x64 tiles (was 32x32) — writes become 64 lanes x 2B = 128B
// full-wave segments (was 64B half-segments), 4x work per block (1728 blocks).
// LDS 64x65 fp32; stride-65 transposed read is conflict-free (65 ≡ 1 mod 32).
// block 0 also zeroes the 32 stat accumulators (red_x[16] + red2[16]) —
// stream-serial with stats_partial / gemm epilogues that atomicAdd into them.
// (R12 lesson: do NOT merge stats/colsums here — 21-block colsum tail idles
//  the machine for ~20 µs. Keep the R11 split.)
// ---------------------------------------------------------------------------
__global__ __launch_bounds__(256) void transpose_all(
    const float* __restrict__ w_qkv, const float* __restrict__ w_out,
    const float* __restrict__ w1, const float* __restrict__ w2,
    bf16* __restrict__ t_qkv, bf16* __restrict__ t_out,
    bf16* __restrict__ t1, bf16* __restrict__ t2,
    float* __restrict__ zstats) {
  const int t = blockIdx.x;
  if (t == 0 && threadIdx.x < 32) zstats[threadIdx.x] = 0.f;
  const float* in; bf16* out; int R, C, idx;
  if (t < 432)       { in = w_qkv; out = t_qkv; R = 768;  C = 2304; idx = t; }
  else if (t < 576)  { in = w_out; out = t_out; R = 768;  C = 768;  idx = t - 432; }
  else if (t < 1152) { in = w1;    out = t1;    R = 768;  C = 3072; idx = t - 576; }
  else               { in = w2;    out = t2;    R = 3072; C = 768;  idx = t - 1152; }
  const int nbx = C >> 6;
  const int bx = (idx % nbx) * 64, by = (idx / nbx) * 64;
  __shared__ float tt[64][65];
  const int tx = threadIdx.x & 63, ty = threadIdx.x >> 6;  // ty: 0..3
#pragma unroll
  for (int rr = 0; rr < 64; rr += 4)
    tt[ty + rr][tx] = in[(long)(by + ty + rr) * C + bx + tx];
  __syncthreads();
#pragma unroll
  for (int rr = 0; rr < 64; rr += 4)
    out[(long)(bx + ty + rr) * R + by + tx] = __float2bfloat16(tt[tx][ty + rr]);
}

// ---------------------------------------------------------------------------
// stats partials + bf16 cast of x (768 blocks; atomicAdd raw sums -> red_x)
// |  colsum(wt1) (48 blocks)  |  colsum(wt_qkv) (36 blocks).
// red_x zeroed by transpose_all (stream-serial).
// ---------------------------------------------------------------------------
__global__ __launch_bounds__(256) void stats_partial(const float* __restrict__ x,
                                                     float* __restrict__ red_x,
                                                     const bf16* __restrict__ wt1,
                                                     const bf16* __restrict__ wt_qkv,
                                                     float* __restrict__ cs1,
                                                     float* __restrict__ csq,
                                                     bf16* __restrict__ xb) {
  if (blockIdx.x >= 768) {                       // colsum over K of weight rows
    const bf16* wsrc; float* cdst; int bi;
    if (blockIdx.x < 816) { wsrc = wt1;    cdst = cs1; bi = blockIdx.x - 768; }
    else                  { wsrc = wt_qkv; cdst = csq; bi = blockIdx.x - 816; }
    const int row = bi * 64 + (threadIdx.x >> 2);
    const int part = threadIdx.x & 3;
    const bf16* wr = wsrc + (long)row * 768 + part * 192;
    float s = 0.f;
#pragma unroll
    for (int u = 0; u < 24; ++u) {
      short8 v = *(const short8*)(wr + u * 8);
#pragma unroll
      for (int e = 0; e < 8; ++e) s += b2f(v[e]);
    }
    s += __shfl_xor(s, 1, 64);
    s += __shfl_xor(s, 2, 64);
    if (part == 0) cdst[row] = s;
    return;
  }
  const long off = (long)blockIdx.x * 8192;
  float s = 0.f, s2 = 0.f;
#pragma unroll
  for (int it = 0; it < 4; ++it) {
    const long i = off + ((long)threadIdx.x + it * 256) * 8;
    float4 v0 = *(const float4*)(x + i);
    float4 v1 = *(const float4*)(x + i + 4);
    s += v0.x + v0.y + v0.z + v0.w + v1.x + v1.y + v1.z + v1.w;
    s2 += v0.x * v0.x + v0.y * v0.y + v0.z * v0.z + v0.w * v0.w +
          v1.x * v1.x + v1.y * v1.y + v1.z * v1.z + v1.w * v1.w;
    __align__(16) bf16 tmp[8];
    tmp[0] = __float2bfloat16(v0.x); tmp[1] = __float2bfloat16(v0.y);
    tmp[2] = __float2bfloat16(v0.z); tmp[3] = __float2bfloat16(v0.w);
    tmp[4] = __float2bfloat16(v1.x); tmp[5] = __float2bfloat16(v1.y);
    tmp[6] = __float2bfloat16(v1.z); tmp[7] = __float2bfloat16(v1.w);
    *(short8*)(xb + i) = *(const short8*)tmp;
  }
#pragma unroll
  for (int o = 1; o < 64; o <<= 1) { s += __shfl_xor(s, o, 64); s2 += __shfl_xor(s2, o, 64); }
  __shared__ float sh[8];
  const int wave = threadIdx.x >> 6, lane = threadIdx.x & 63;
  if (lane == 0) { sh[wave * 2] = s; sh[wave * 2 + 1] = s2; }
  __syncthreads();
  if (threadIdx.x == 0) {
    const int bb = blockIdx.x / 96;            // 96 blocks per batch
    atomicAdd(&red_x[bb * 2],     sh[0] + sh[2] + sh[4] + sh[6]);
    atomicAdd(&red_x[bb * 2 + 1], sh[1] + sh[3] + sh[5] + sh[7]);
  }
}

// ---------------------------------------------------------------------------
// MFMA GEMM: m97-exact structure (R3-measured best). TM=TN=128, BK=64,
// 4 waves (64x64/wave, acc[4][4]), SINGLE-buffered 32 KB LDS -> 3 blocks/CU.
// Two barriers per K-step; cross-block wave overlap hides the vmcnt drain.
// R0/R4/R5: dbuf, 8-wave, and 2-wave variants all regress.
// R9: inline stat-partial reduction in EPI-0 cost +8-10 µs.
// R10: setprio on MFMA clusters is null-to-harmful (barrier-locked waves).
// XOR 16B-chunk swizzle on both tiles.
// EPI 0: IN folded as affine (v = rs*(acc - mu*cs[n])), then QKV scatter
// EPI 1: v = acc+bias+res; outf fp32, outb0 bf16 copy (+ fused IN-stats)
// EPI 2: v = rs*(acc - mu*cs[n]) + bias (IN folded); gelu; outb0 bf16
// EPI 3: v = acc+bias+res; outf fp32 only
// ---------------------------------------------------------------------------
template <int EPI, bool STATS>
__global__ __launch_bounds__(256) void gemm_k(
    const bf16* __restrict__ A, const bf16* __restrict__ Bt,
    int M, int N, int K,
    const float* __restrict__ biasf, const float* __restrict__ resf,
    const float* __restrict__ cs, const float* __restrict__ stat_in,
    float* __restrict__ outf,
    bf16* __restrict__ outb0, bf16* __restrict__ outb1, bf16* __restrict__ outb2,
    float* __restrict__ statp) {
  __shared__ __align__(16) bf16 As[128 * 64];
  __shared__ __align__(16) bf16 Bs[128 * 64];
  __shared__ float sred[8];
  const int tid = threadIdx.x;
  const int bm = blockIdx.x * 128, bn = blockIdx.y * 128;
  const int wave = tid >> 6, lane = tid & 63;
  const int quad = lane >> 4, l16 = lane & 15;
  const int wm = (wave >> 1) * 64, wn = (wave & 1) * 64;
  const int swz = l16 & 7;            // row&7 for all fragment rows

  f32x4 acc[4][4];
#pragma unroll
  for (int i = 0; i < 4; ++i)
#pragma unroll
    for (int j = 0; j < 4; ++j) acc[i][j] = (f32x4){0.f, 0.f, 0.f, 0.f};

  const int srow = tid >> 3;                 // 0..31
  const int sgc = (tid & 7) ^ (srow & 7);    // swizzled global chunk for this LDS slot
  const bf16* Ab = A + (long)(bm + srow) * K + sgc * 8;
  const bf16* Bb = Bt + (long)(bn + srow) * K + sgc * 8;

  auto stage = [&](int k0) {
#pragma unroll
    for (int s = 0; s < 4; ++s)
      gl2lds16(Ab + (long)(s * 32) * K + k0, &As[0] + s * 2048 + tid * 8);
#pragma unroll
    for (int s = 0; s < 4; ++s)
      gl2lds16(Bb + (long)(s * 32) * K + k0, &Bs[0] + s * 2048 + tid * 8);
  };

  stage(0);
  const int nk = K >> 6;
  for (int kt = 0; kt < nk; ++kt) {
    __syncthreads();                  // stage(kt) landed (per-wave vmcnt drain)
    short8 a[2][4], b[2][4];
#pragma unroll
    for (int kk = 0; kk < 2; ++kk) {
      const int co = ((kk * 4 + quad) ^ swz) * 8;
#pragma unroll
      for (int i = 0; i < 4; ++i)
        a[kk][i] = *(const short8*)(&As[0] + (wm + i * 16 + l16) * 64 + co);
#pragma unroll
      for (int j = 0; j < 4; ++j)
        b[kk][j] = *(const short8*)(&Bs[0] + (wn + j * 16 + l16) * 64 + co);
    }
    __syncthreads();                  // all waves done reading; buffer free
    if (kt + 1 < nk) stage((kt + 1) * 64);
#pragma unroll
    for (int kk = 0; kk < 2; ++kk)
#pragma unroll
      for (int i = 0; i < 4; ++i)
#pragma unroll
        for (int j = 0; j < 4; ++j)
          acc[i][j] = __builtin_amdgcn_mfma_f32_16x16x32_bf16(a[kk][i], b[kk][j], acc[i][j], 0, 0, 0);
  }

  // epilogue: D[m][n] at m = quad*4+reg (+16*i), n = l16 (+16*j)
  const int m0 = bm + wm + quad * 4;
  const int n0 = bn + wn + l16;
  const int batch = bm >> 10;         // 128-row tile always within one batch
  float mu = 0.f, rs = 0.f;
  if (EPI == 0 || EPI == 2) {
    const float s1 = stat_in[batch * 2], s2v = stat_in[batch * 2 + 1];
    mu = s1 * (1.0f / SD_);
    rs = rsqrtf(s2v * (1.0f / SD_) - mu * mu + 1e-5f);
  }
  float ts = 0.f, ts2 = 0.f;
#pragma unroll
  for (int i = 0; i < 4; ++i) {
#pragma unroll
    for (int j = 0; j < 4; ++j) {
      const int n = n0 + j * 16;
#pragma unroll
      for (int r = 0; r < 4; ++r) {
        const int m = m0 + i * 16 + r;
        float v = acc[i][j][r];
        if (EPI == 0) {
          v = rs * (v - mu * cs[n]);    // instance-norm-1 folded (A was raw x)
          const int t = n / D_;
          const int rr2 = n - t * D_;
          const int hh = rr2 >> 6, dd = rr2 & 63;
          const int bb = m >> 10, ss = m & 1023;
          const long hoff = (long)(bb * H_ + hh);
          if (t == 0)      outb0[(hoff * S_ + ss) * HD_ + dd] = __float2bfloat16(v * QSCALE);
          else if (t == 1) outb1[(hoff * S_ + ss) * HD_ + dd] = __float2bfloat16(v);
          else             outb2[(hoff * HD_ + dd) * S_ + ss] = __float2bfloat16(v);
        } else if (EPI == 1) {
          v += biasf[n] + resf[(long)m * N + n];
          outf[(long)m * N + n] = v;
          outb0[(long)m * N + n] = __float2bfloat16(v);
          if (STATS) { ts += v; ts2 += v * v; }
        } else if (EPI == 2) {
          v = rs * (v - mu * cs[n]) + biasf[n];
          // tanh-form GELU via sigmoid: v * sigm(1.59577(v + 0.044715 v^3))
          float u = v * v;
          float y = v * (1.0f + 0.044715f * u) * 0.7978845608028654f;
          float z = fast_exp2(y * -2.885390081777927f);    // e^{-2y}
          v = v * __builtin_amdgcn_rcpf(1.0f + z);
          outb0[(long)m * N + n] = __float2bfloat16(v);
        } else {
          v += biasf[n] + resf[(long)m * N + n];
          outf[(long)m * N + n] = v;
        }
      }
    }
  }
  if (STATS) {                        // fused instance-norm partial sums
#pragma unroll
    for (int o = 1; o < 64; o <<= 1) { ts += __shfl_xor(ts, o, 64); ts2 += __shfl_xor(ts2, o, 64); }
    if (lane == 0) { sred[wave * 2] = ts; sred[wave * 2 + 1] = ts2; }
    __syncthreads();
    if (tid == 0) {
      atomicAdd(&statp[batch * 2], sred[0] + sred[2] + sred[4] + sred[6]);
      atomicAdd(&statp[batch * 2 + 1], sred[1] + sred[3] + sred[5] + sred[7]);
    }
  }
}

// ---------------------------------------------------------------------------
// flash attention: 4 waves x 64 q-rows per block, grid (B*H, S/64).
// (R11-measured best total.) In-reg P (R6), issue-early prefetch + fast_exp2
// + fastbf (R7). No setprio (R10 A/B: harmful).
// V B-fragment = two 8B runs/lane (kv 32kk+4q, 32kk+16+4q) -> 2x ds_read_b64.
// K/V LDS dbuf + XOR chunk swizzle; no-max softmax (q pre-scaled).
// ---------------------------------------------------------------------------
__global__ __launch_bounds__(256) void attn64(const bf16* __restrict__ q,
                                              const bf16* __restrict__ k,
                                              const bf16* __restrict__ vt,
                                              bf16* __restrict__ o) {
  __shared__ __align__(16) bf16 Ks[2][64 * 64];
  __shared__ __align__(16) bf16 Vs[2][64 * 64];   // [d][kv]
  const int bh = blockIdx.x, qt = blockIdx.y;
  const int tid = threadIdx.x, wave = tid >> 6, lane = tid & 63;
  const int quad = lane >> 4, l16 = lane & 15;
  const int sw = (l16 & 7) ^ ((l16 >> 3) & 1);   // swz(row) for rows ≡ l16 (mod 16)
  const long base = (long)bh * (S_ * HD_);
  const bf16* kg = k + base;
  const bf16* vg = vt + base;

  const int srow = tid >> 3;                                    // 0..31
  const int scg = (tid & 7) ^ (srow & 7) ^ ((srow >> 3) & 1);   // global chunk to fetch

  short8 aq[2];
#pragma unroll
  for (int kk = 0; kk < 2; ++kk)
    aq[kk] = *(const short8*)(q + base + (long)(qt * 64 + wave * 16 + l16) * HD_ +
                              kk * 32 + quad * 8);

  // stage tile 0 (256 lanes x 16B x 2 calls = full 8KB tile per buffer)
  gl2lds16(kg + (long)srow * HD_ + scg * 8, &Ks[0][0] + tid * 8);
  gl2lds16(kg + (long)(32 + srow) * HD_ + scg * 8, &Ks[0][0] + 2048 + tid * 8);
  gl2lds16(vg + (long)srow * S_ + scg * 8, &Vs[0][0] + tid * 8);
  gl2lds16(vg + (long)(32 + srow) * S_ + scg * 8, &Vs[0][0] + 2048 + tid * 8);

  // running next-tile prefetch pointers (K advances 64 rows, V advances 64 kv)
  const bf16* kp = kg + (long)(64 + srow) * HD_ + scg * 8;
  const bf16* vp = vg + (long)srow * S_ + 64 + scg * 8;

  f32x4 oacc[4];
#pragma unroll
  for (int j = 0; j < 4; ++j) oacc[j] = (f32x4){0.f, 0.f, 0.f, 0.f};
  float lp = 0.f;                       // per-lane partial sum for q-row l16

  // V b64 half-chunk offsets (bf16 elements), fixed per lane:
  //   chunk g = 4*kk + (quad>>1) (+2 for the hi run), half = quad&1
  const int vh = (quad & 1) * 4;

#define ATTN_STEP(CUR, DOPREF)                                                 \
  {                                                                            \
    __syncthreads();                                                           \
    if (DOPREF) {          /* issue-early: full step covers the latency */     \
      gl2lds16(kp, &Ks[(CUR) ^ 1][0] + tid * 8);                               \
      gl2lds16(kp + 32 * HD_, &Ks[(CUR) ^ 1][0] + 2048 + tid * 8);             \
      gl2lds16(vp, &Vs[(CUR) ^ 1][0] + tid * 8);                               \
      gl2lds16(vp + 32 * (long)S_, &Vs[(CUR) ^ 1][0] + 2048 + tid * 8);        \
      kp += 64 * HD_;                                                          \
      vp += 64;                                                                \
    }                                                                          \
    f32x4 s[4];                                                                \
    _Pragma("unroll")                                                          \
    for (int i = 0; i < 4; ++i) s[i] = (f32x4){0.f, 0.f, 0.f, 0.f};            \
    _Pragma("unroll")                                                          \
    for (int kk = 0; kk < 2; ++kk) {                                           \
      _Pragma("unroll")                                                        \
      for (int i = 0; i < 4; ++i) {                                            \
        short8 ak = *(const short8*)(&Ks[CUR][0] + (i * 16 + l16) * 64 +       \
                                     (((kk * 4 + quad) ^ sw) * 8));            \
        s[i] = __builtin_amdgcn_mfma_f32_16x16x32_bf16(ak, aq[kk], s[i], 0, 0, 0); \
      }                                                                        \
    }                                                                          \
    float pe[4][4];                                                            \
    _Pragma("unroll")                                                          \
    for (int i = 0; i < 4; ++i) {                                              \
      _Pragma("unroll")                                                        \
      for (int r = 0; r < 4; ++r) { pe[i][r] = fast_exp2(s[i][r]); lp += pe[i][r]; } \
    }                                                                          \
    union { short8 v; bf16 b[8]; } af[2];                                      \
    _Pragma("unroll")                                                          \
    for (int r = 0; r < 4; ++r) {                                              \
      af[0].b[r]     = fastbf(pe[0][r]);                                       \
      af[0].b[4 + r] = fastbf(pe[1][r]);                                       \
      af[1].b[r]     = fastbf(pe[2][r]);                                       \
      af[1].b[4 + r] = fastbf(pe[3][r]);                                       \
    }                                                                          \
    _Pragma("unroll")                                                          \
    for (int kk = 0; kk < 2; ++kk) {                                           \
      const int g0 = ((4 * kk + (quad >> 1)) ^ sw) * 8 + vh;                   \
      const int g1 = ((4 * kk + 2 + (quad >> 1)) ^ sw) * 8 + vh;               \
      _Pragma("unroll")                                                        \
      for (int dj = 0; dj < 4; ++dj) {                                         \
        const bf16* vrow = &Vs[CUR][0] + (dj * 16 + l16) * 64;                 \
        union { short8 v; uint2 u[2]; } bv;                                    \
        bv.u[0] = *(const uint2*)(vrow + g0);                                  \
        bv.u[1] = *(const uint2*)(vrow + g1);                                  \
        oacc[dj] = __builtin_amdgcn_mfma_f32_16x16x32_bf16(af[kk].v, bv.v, oacc[dj], 0, 0, 0); \
      }                                                                        \
    }                                                                          \
  }

  for (int c = 0; c < 16; c += 2) {
    ATTN_STEP(0, true)
    ATTN_STEP(1, (c < 14))
  }
#undef ATTN_STEP

  // reduce row sums: lane's lp covers quad's 16-kv slices; sum across quads
  float lt = lp;
  lt += __shfl_xor(lt, 16, 64);
  lt += __shfl_xor(lt, 32, 64);       // lane now holds full sum for q-row l16

  const int b = bh / H_, hh = bh - b * H_;
#pragma unroll
  for (int r = 0; r < 4; ++r) {
    const float inv = 1.0f / __shfl(lt, quad * 4 + r, 64);
    const int sg = qt * 64 + wave * 16 + quad * 4 + r;
    const long rowoff = ((long)b * S_ + sg) * D_ + hh * HD_;
#pragma unroll
    for (int dj = 0; dj < 4; ++dj)
      o[rowoff + dj * 16 + l16] = __float2bfloat16(oacc[dj][r] * inv);
  }
}

// ---------------------------------------------------------------------------
extern "C" void kernel_launch(void* const* d_in, const int* in_sizes, int n_in,
                              void* d_out, int out_size, void* d_ws, size_t ws_size,
                              hipStream_t stream) {
  const float* x     = (const float*)d_in[0];
  const float* w_qkv = (const float*)d_in[1];
  const float* w_out = (const float*)d_in[2];
  const float* b_out = (const float*)d_in[3];
  const float* w1    = (const float*)d_in[4];
  const float* b1    = (const float*)d_in[5];
  const float* w2    = (const float*)d_in[6];
  const float* b2    = (const float*)d_in[7];
  float* out = (float*)d_out;

  // workspace layout
  bf16* wt_qkv = (bf16*)d_ws;                 // [2304][768]
  bf16* wt_out = wt_qkv + 2304 * 768;         // [768][768]
  bf16* wt1    = wt_out + 768 * 768;          // [3072][768]
  bf16* wt2    = wt1 + 3072 * 768;            // [768][3072]
  bf16* qb     = wt2 + 768 * 3072;            // [B,H,S,HD] = 6291456
  bf16* kb     = qb + 6291456;
  bf16* vtb    = kb + 6291456;                // [B,H,HD,S]
  bf16* ob     = vtb + 6291456;               // attention out [B,S,D] bf16
  float* x1f   = (float*)(ob + 6291456);      // residual-1 fp32 [B,S,D]
  bf16* hb     = (bf16*)(x1f + 6291456);      // xb (bf16 x); later reused as x1b
  float* redp  = (float*)(hb + 6291456);      // (unused slot, kept for layout)
  float* red_x = redp + 1536;                 // 16 raw sums (norm-1, atomics)
  float* red2  = red_x + 16;                  // 16 raw sums (norm-2, atomics)
  float* cs1   = red2 + 16;                   // colsum(w1)[3072]
  float* csq   = cs1 + 3072;                  // colsum(w_qkv)[2304]
  bf16* gb     = qb;                          // MLP hidden reuses qb..ob (dead)
  bf16* xb     = hb;                          // bf16 cast of x
  bf16* x1b    = hb;                          // bf16 copy of x1 (xb dead after QKV)

  // 1. all weight transposes, 64x64 tiles (+ zero red_x/red2: 32 floats)
  transpose_all<<<1728, 256, 0, stream>>>(w_qkv, w_out, w1, w2,
                                          wt_qkv, wt_out, wt1, wt2, red_x);

  // 2. stats(x) -> red_x (atomics) + bf16 cast -> xb; colsums -> cs1/csq
  stats_partial<<<768 + 48 + 36, 256, 0, stream>>>(x, red_x, wt1, wt_qkv,
                                                   cs1, csq, xb);

  // 3. QKV projection on RAW xb; instance-norm-1 folded into epilogue; scatter
  gemm_k<0, false><<<dim3(64, 18), 256, 0, stream>>>(
      xb, wt_qkv, 8192, 2304, 768, nullptr, nullptr, csq, red_x,
      nullptr, qb, kb, vtb, nullptr);
  // 4. attention (head-major grid; 4 waves x 64 q-rows)
  attn64<<<dim3(B_ * H_, 16), 256, 0, stream>>>(qb, kb, vtb, ob);

  // 5. out-projection + bias + residual -> x1f fp32 + x1b bf16, stats -> red2
  gemm_k<1, true><<<dim3(64, 6), 256, 0, stream>>>(
      ob, wt_out, 8192, 768, 768, b_out, x, nullptr, nullptr,
      x1f, x1b, nullptr, nullptr, red2);

  // 6. MLP up on UNNORMALIZED x1b; instance-norm-2 folded; tanh-GELU -> gb
  gemm_k<2, false><<<dim3(64, 24), 256, 0, stream>>>(
      x1b, wt1, 8192, 3072, 768, b1, nullptr, cs1, red2,
      nullptr, gb, nullptr, nullptr, nullptr);

  // 7. MLP down + bias + residual -> out
  gemm_k<3, false><<<dim3(64, 6), 256, 0, stream>>>(
      gb, wt2, 8192, 768, 3072, b2, x1f, nullptr, nullptr,
      out, nullptr, nullptr, nullptr, nullptr);
}

// Round 15
// 331.545 us; speedup vs baseline: 1.1164x; 1.0090x over previous
//
#include <hip/hip_runtime.h>
#include <hip/hip_bf16.h>

typedef __hip_bfloat16 bf16;
typedef __attribute__((ext_vector_type(8))) short short8;   // 8 bf16 = 4 VGPRs (MFMA A/B frag)
typedef __attribute__((ext_vector_type(4))) float f32x4;    // MFMA C/D frag

#define B_   8
#define S_   1024
#define D_   768
#define H_   12
#define HD_  64
#define MLP_ 3072
#define SD_  (S_ * D_)          // 786432 elements per batch

#define QSCALE 0.18033688011112042f   // log2(e) / 8  (softmax scale folded into q)

__device__ __forceinline__ float b2f(short h) {
  union { unsigned u; float f; } w;
  w.u = ((unsigned)(unsigned short)h) << 16;
  return w.f;
}

// single-instruction 2^x (v_exp_f32; ~1-2 ulp, fine under bf16 rounding)
__device__ __forceinline__ float fast_exp2(float x) {
  float r;
  asm("v_exp_f32 %0, %1" : "=v"(r) : "v"(x));
  return r;
}

// branch-free RNE float->bf16 (exact RNE for finite non-NaN inputs; 3 VALU)
__device__ __forceinline__ bf16 fastbf(float f) {
  union { float f; unsigned u; } w; w.f = f;
  unsigned r = (w.u + 0x7FFF + ((w.u >> 16) & 1)) >> 16;
  union { unsigned short s; bf16 b; } o; o.s = (unsigned short)r;
  return o.b;
}

// async global->LDS, 16B per lane; LDS dest must equal wave-uniform base + lane*16B
__device__ __forceinline__ void gl2lds16(const bf16* g, bf16* l) {
  __builtin_amdgcn_global_load_lds(
      (const __attribute__((address_space(1))) unsigned*)(const void*)g,
      (__attribute__((address_space(3))) unsigned*)(void*)l, 16, 0, 0);
}

// ---------------------------------------------------------------------------
// all 4 weight transposes (fp32 [R][C] -> bf16 [C][R]) in one launch.
// 64x64 tiles: writes are 128B full-wave segments; LDS 64x65 fp32
// (stride-65 transposed read conflict-free). block 0 zeroes the 32 stat
// accumulators (red_x[16] + red2[16]) — stream-serial with later atomics.
// (R12 lesson: do NOT merge stats/colsums here — 21-block tail idles the
//  machine. R9 lesson: EPI-0 must read precomputed totals.)
// ---------------------------------------------------------------------------
__global__ __launch_bounds__(256) void transpose_all(
    const float* __restrict__ w_qkv, const float* __restrict__ w_out,
    const float* __restrict__ w1, const float* __restrict__ w2,
    bf16* __restrict__ t_qkv, bf16* __restrict__ t_out,
    bf16* __restrict__ t1, bf16* __restrict__ t2,
    float* __restrict__ zstats) {
  const int t = blockIdx.x;
  if (t == 0 && threadIdx.x < 32) zstats[threadIdx.x] = 0.f;
  const float* in; bf16* out; int R, C, idx;
  if (t < 432)       { in = w_qkv; out = t_qkv; R = 768;  C = 2304; idx = t; }
  else if (t < 576)  { in = w_out; out = t_out; R = 768;  C = 768;  idx = t - 432; }
  else if (t < 1152) { in = w1;    out = t1;    R = 768;  C = 3072; idx = t - 576; }
  else               { in = w2;    out = t2;    R = 3072; C = 768;  idx = t - 1152; }
  const int nbx = C >> 6;
  const int bx = (idx % nbx) * 64, by = (idx / nbx) * 64;
  __shared__ float tt[64][65];
  const int tx = threadIdx.x & 63, ty = threadIdx.x >> 6;  // ty: 0..3
#pragma unroll
  for (int rr = 0; rr < 64; rr += 4)
    tt[ty + rr][tx] = in[(long)(by + ty + rr) * C + bx + tx];
  __syncthreads();
#pragma unroll
  for (int rr = 0; rr < 64; rr += 4)
    out[(long)(bx + ty + rr) * R + by + tx] = __float2bfloat16(tt[tx][ty + rr]);
}

// ---------------------------------------------------------------------------
// stats partials + bf16 cast of x (768 blocks; atomicAdd raw sums -> red_x)
// |  colsum(wt1) (48 blocks)  |  colsum(wt_qkv) (36 blocks).
// red_x zeroed by transpose_all (stream-serial).
// ---------------------------------------------------------------------------
__global__ __launch_bounds__(256) void stats_partial(const float* __restrict__ x,
                                                     float* __restrict__ red_x,
                                                     const bf16* __restrict__ wt1,
                                                     const bf16* __restrict__ wt_qkv,
                                                     float* __restrict__ cs1,
                                                     float* __restrict__ csq,
                                                     bf16* __restrict__ xb) {
  if (blockIdx.x >= 768) {                       // colsum over K of weight rows
    const bf16* wsrc; float* cdst; int bi;
    if (blockIdx.x < 816) { wsrc = wt1;    cdst = cs1; bi = blockIdx.x - 768; }
    else                  { wsrc = wt_qkv; cdst = csq; bi = blockIdx.x - 816; }
    const int row = bi * 64 + (threadIdx.x >> 2);
    const int part = threadIdx.x & 3;
    const bf16* wr = wsrc + (long)row * 768 + part * 192;
    float s = 0.f;
#pragma unroll
    for (int u = 0; u < 24; ++u) {
      short8 v = *(const short8*)(wr + u * 8);
#pragma unroll
      for (int e = 0; e < 8; ++e) s += b2f(v[e]);
    }
    s += __shfl_xor(s, 1, 64);
    s += __shfl_xor(s, 2, 64);
    if (part == 0) cdst[row] = s;
    return;
  }
  const long off = (long)blockIdx.x * 8192;
  float s = 0.f, s2 = 0.f;
#pragma unroll
  for (int it = 0; it < 4; ++it) {
    const long i = off + ((long)threadIdx.x + it * 256) * 8;
    float4 v0 = *(const float4*)(x + i);
    float4 v1 = *(const float4*)(x + i + 4);
    s += v0.x + v0.y + v0.z + v0.w + v1.x + v1.y + v1.z + v1.w;
    s2 += v0.x * v0.x + v0.y * v0.y + v0.z * v0.z + v0.w * v0.w +
          v1.x * v1.x + v1.y * v1.y + v1.z * v1.z + v1.w * v1.w;
    __align__(16) bf16 tmp[8];
    tmp[0] = __float2bfloat16(v0.x); tmp[1] = __float2bfloat16(v0.y);
    tmp[2] = __float2bfloat16(v0.z); tmp[3] = __float2bfloat16(v0.w);
    tmp[4] = __float2bfloat16(v1.x); tmp[5] = __float2bfloat16(v1.y);
    tmp[6] = __float2bfloat16(v1.z); tmp[7] = __float2bfloat16(v1.w);
    *(short8*)(xb + i) = *(const short8*)tmp;
  }
#pragma unroll
  for (int o = 1; o < 64; o <<= 1) { s += __shfl_xor(s, o, 64); s2 += __shfl_xor(s2, o, 64); }
  __shared__ float sh[8];
  const int wave = threadIdx.x >> 6, lane = threadIdx.x & 63;
  if (lane == 0) { sh[wave * 2] = s; sh[wave * 2 + 1] = s2; }
  __syncthreads();
  if (threadIdx.x == 0) {
    const int bb = blockIdx.x / 96;            // 96 blocks per batch
    atomicAdd(&red_x[bb * 2],     sh[0] + sh[2] + sh[4] + sh[6]);
    atomicAdd(&red_x[bb * 2 + 1], sh[1] + sh[3] + sh[5] + sh[7]);
  }
}

// ---------------------------------------------------------------------------
// MFMA GEMM: m97-exact structure (R3-measured best). TM=TN=128, BK=64,
// 4 waves (64x64/wave, acc[4][4]), SINGLE-buffered 32 KB LDS -> 3 blocks/CU.
// Two barriers per K-step; cross-block wave overlap hides the vmcnt drain.
// R0/R4/R5: dbuf, 8-wave, and 2-wave variants all regress.
// R9: inline stat-partial reduction in EPI-0 cost +8-10 µs.
// R10: setprio on MFMA clusters is null-to-harmful (barrier-locked waves).
// XOR 16B-chunk swizzle on both tiles.
// EPI 0: IN folded as affine (v = rs*(acc - mu*cs[n])), then QKV scatter
// EPI 1: v = acc+bias+res; outf fp32, outb0 bf16 copy (+ fused IN-stats)
// EPI 2: v = rs*(acc - mu*cs[n]) + bias (IN folded); gelu; outb0 bf16
// EPI 3: v = acc+bias+res; outf fp32 only
// ---------------------------------------------------------------------------
template <int EPI, bool STATS>
__global__ __launch_bounds__(256) void gemm_k(
    const bf16* __restrict__ A, const bf16* __restrict__ Bt,
    int M, int N, int K,
    const float* __restrict__ biasf, const float* __restrict__ resf,
    const float* __restrict__ cs, const float* __restrict__ stat_in,
    float* __restrict__ outf,
    bf16* __restrict__ outb0, bf16* __restrict__ outb1, bf16* __restrict__ outb2,
    float* __restrict__ statp) {
  __shared__ __align__(16) bf16 As[128 * 64];
  __shared__ __align__(16) bf16 Bs[128 * 64];
  __shared__ float sred[8];
  const int tid = threadIdx.x;
  const int bm = blockIdx.x * 128, bn = blockIdx.y * 128;
  const int wave = tid >> 6, lane = tid & 63;
  const int quad = lane >> 4, l16 = lane & 15;
  const int wm = (wave >> 1) * 64, wn = (wave & 1) * 64;
  const int swz = l16 & 7;            // row&7 for all fragment rows

  f32x4 acc[4][4];
#pragma unroll
  for (int i = 0; i < 4; ++i)
#pragma unroll
    for (int j = 0; j < 4; ++j) acc[i][j] = (f32x4){0.f, 0.f, 0.f, 0.f};

  const int srow = tid >> 3;                 // 0..31
  const int sgc = (tid & 7) ^ (srow & 7);    // swizzled global chunk for this LDS slot
  const bf16* Ab = A + (long)(bm + srow) * K + sgc * 8;
  const bf16* Bb = Bt + (long)(bn + srow) * K + sgc * 8;

  auto stage = [&](int k0) {
#pragma unroll
    for (int s = 0; s < 4; ++s)
      gl2lds16(Ab + (long)(s * 32) * K + k0, &As[0] + s * 2048 + tid * 8);
#pragma unroll
    for (int s = 0; s < 4; ++s)
      gl2lds16(Bb + (long)(s * 32) * K + k0, &Bs[0] + s * 2048 + tid * 8);
  };

  stage(0);
  const int nk = K >> 6;
  for (int kt = 0; kt < nk; ++kt) {
    __syncthreads();                  // stage(kt) landed (per-wave vmcnt drain)
    short8 a[2][4], b[2][4];
#pragma unroll
    for (int kk = 0; kk < 2; ++kk) {
      const int co = ((kk * 4 + quad) ^ swz) * 8;
#pragma unroll
      for (int i = 0; i < 4; ++i)
        a[kk][i] = *(const short8*)(&As[0] + (wm + i * 16 + l16) * 64 + co);
#pragma unroll
      for (int j = 0; j < 4; ++j)
        b[kk][j] = *(const short8*)(&Bs[0] + (wn + j * 16 + l16) * 64 + co);
    }
    __syncthreads();                  // all waves done reading; buffer free
    if (kt + 1 < nk) stage((kt + 1) * 64);
#pragma unroll
    for (int kk = 0; kk < 2; ++kk)
#pragma unroll
      for (int i = 0; i < 4; ++i)
#pragma unroll
        for (int j = 0; j < 4; ++j)
          acc[i][j] = __builtin_amdgcn_mfma_f32_16x16x32_bf16(a[kk][i], b[kk][j], acc[i][j], 0, 0, 0);
  }

  // epilogue: D[m][n] at m = quad*4+reg (+16*i), n = l16 (+16*j)
  const int m0 = bm + wm + quad * 4;
  const int n0 = bn + wn + l16;
  const int batch = bm >> 10;         // 128-row tile always within one batch
  float mu = 0.f, rs = 0.f;
  if (EPI == 0 || EPI == 2) {
    const float s1 = stat_in[batch * 2], s2v = stat_in[batch * 2 + 1];
    mu = s1 * (1.0f / SD_);
    rs = rsqrtf(s2v * (1.0f / SD_) - mu * mu + 1e-5f);
  }
  float ts = 0.f, ts2 = 0.f;
#pragma unroll
  for (int i = 0; i < 4; ++i) {
#pragma unroll
    for (int j = 0; j < 4; ++j) {
      const int n = n0 + j * 16;
#pragma unroll
      for (int r = 0; r < 4; ++r) {
        const int m = m0 + i * 16 + r;
        float v = acc[i][j][r];
        if (EPI == 0) {
          v = rs * (v - mu * cs[n]);    // instance-norm-1 folded (A was raw x)
          const int t = n / D_;
          const int rr2 = n - t * D_;
          const int hh = rr2 >> 6, dd = rr2 & 63;
          const int bb = m >> 10, ss = m & 1023;
          const long hoff = (long)(bb * H_ + hh);
          if (t == 0)      outb0[(hoff * S_ + ss) * HD_ + dd] = __float2bfloat16(v * QSCALE);
          else if (t == 1) outb1[(hoff * S_ + ss) * HD_ + dd] = __float2bfloat16(v);
          else             outb2[(hoff * HD_ + dd) * S_ + ss] = __float2bfloat16(v);
        } else if (EPI == 1) {
          v += biasf[n] + resf[(long)m * N + n];
          outf[(long)m * N + n] = v;
          outb0[(long)m * N + n] = __float2bfloat16(v);
          if (STATS) { ts += v; ts2 += v * v; }
        } else if (EPI == 2) {
          v = rs * (v - mu * cs[n]) + biasf[n];
          // tanh-form GELU via sigmoid: v * sigm(1.59577(v + 0.044715 v^3))
          float u = v * v;
          float y = v * (1.0f + 0.044715f * u) * 0.7978845608028654f;
          float z = fast_exp2(y * -2.885390081777927f);    // e^{-2y}
          v = v * __builtin_amdgcn_rcpf(1.0f + z);
          outb0[(long)m * N + n] = __float2bfloat16(v);
        } else {
          v += biasf[n] + resf[(long)m * N + n];
          outf[(long)m * N + n] = v;
        }
      }
    }
  }
  if (STATS) {                        // fused instance-norm partial sums
#pragma unroll
    for (int o = 1; o < 64; o <<= 1) { ts += __shfl_xor(ts, o, 64); ts2 += __shfl_xor(ts2, o, 64); }
    if (lane == 0) { sred[wave * 2] = ts; sred[wave * 2 + 1] = ts2; }
    __syncthreads();
    if (tid == 0) {
      atomicAdd(&statp[batch * 2], sred[0] + sred[2] + sred[4] + sred[6]);
      atomicAdd(&statp[batch * 2 + 1], sred[1] + sred[3] + sred[5] + sred[7]);
    }
  }
}

// ---------------------------------------------------------------------------
// flash attention: R14 — 4 waves, 2 q-tiles (128 q-rows) per block,
// grid (B*H, S/128). Targets the measured binding pipe: LDS reads+conflicts
// ≈75% of attn cycles. Each ak (K) and bv (V) fragment loaded from LDS now
// feeds TWO MFMAs (one per q-tile) — total MFMA/VALU unchanged, total LDS
// reads, staging traffic, and barriers HALVED.
// In-reg P (R6), issue-early prefetch + fast_exp2 + fastbf (R7).
// No setprio (R10 A/B: harmful).
// V B-fragment = two 8B runs/lane (kv 32kk+4q, 32kk+16+4q) -> 2x ds_read_b64.
// K/V LDS dbuf + XOR chunk swizzle; no-max softmax (q pre-scaled).
// ---------------------------------------------------------------------------
__global__ __launch_bounds__(256) void attn64(const bf16* __restrict__ q,
                                              const bf16* __restrict__ k,
                                              const bf16* __restrict__ vt,
                                              bf16* __restrict__ o) {
  __shared__ __align__(16) bf16 Ks[2][64 * 64];
  __shared__ __align__(16) bf16 Vs[2][64 * 64];   // [d][kv]
  const int bh = blockIdx.x, qt = blockIdx.y;
  const int tid = threadIdx.x, wave = tid >> 6, lane = tid & 63;
  const int quad = lane >> 4, l16 = lane & 15;
  const int sw = (l16 & 7) ^ ((l16 >> 3) & 1);   // swz(row) for rows ≡ l16 (mod 16)
  const long base = (long)bh * (S_ * HD_);
  const bf16* kg = k + base;
  const bf16* vg = vt + base;

  const int srow = tid >> 3;                                    // 0..31
  const int scg = (tid & 7) ^ (srow & 7) ^ ((srow >> 3) & 1);   // global chunk to fetch

  // two q-tiles per wave: rows qt*128 + qq*64 + wave*16 + l16
  short8 aq[2][2];
#pragma unroll
  for (int qq = 0; qq < 2; ++qq)
#pragma unroll
    for (int kk = 0; kk < 2; ++kk)
      aq[qq][kk] = *(const short8*)(q + base +
                     (long)(qt * 128 + qq * 64 + wave * 16 + l16) * HD_ +
                     kk * 32 + quad * 8);

  // stage tile 0 (256 lanes x 16B x 2 calls = full 8KB tile per buffer)
  gl2lds16(kg + (long)srow * HD_ + scg * 8, &Ks[0][0] + tid * 8);
  gl2lds16(kg + (long)(32 + srow) * HD_ + scg * 8, &Ks[0][0] + 2048 + tid * 8);
  gl2lds16(vg + (long)srow * S_ + scg * 8, &Vs[0][0] + tid * 8);
  gl2lds16(vg + (long)(32 + srow) * S_ + scg * 8, &Vs[0][0] + 2048 + tid * 8);

  // running next-tile prefetch pointers (K advances 64 rows, V advances 64 kv)
  const bf16* kp = kg + (long)(64 + srow) * HD_ + scg * 8;
  const bf16* vp = vg + (long)srow * S_ + 64 + scg * 8;

  f32x4 oacc[2][4];
#pragma unroll
  for (int qq = 0; qq < 2; ++qq)
#pragma unroll
    for (int j = 0; j < 4; ++j) oacc[qq][j] = (f32x4){0.f, 0.f, 0.f, 0.f};
  float lp0 = 0.f, lp1 = 0.f;          // per-lane partial sums, one per q-tile

  // V b64 half-chunk offsets (bf16 elements), fixed per lane
  const int vh = (quad & 1) * 4;

#define ATTN_STEP(CUR, DOPREF)                                                 \
  {                                                                            \
    __syncthreads();                                                           \
    if (DOPREF) {          /* issue-early: full step covers the latency */     \
      gl2lds16(kp, &Ks[(CUR) ^ 1][0] + tid * 8);                               \
      gl2lds16(kp + 32 * HD_, &Ks[(CUR) ^ 1][0] + 2048 + tid * 8);             \
      gl2lds16(vp, &Vs[(CUR) ^ 1][0] + tid * 8);                               \
      gl2lds16(vp + 32 * (long)S_, &Vs[(CUR) ^ 1][0] + 2048 + tid * 8);        \
      kp += 64 * HD_;                                                          \
      vp += 64;                                                                \
    }                                                                          \
    f32x4 s[2][4];                                                             \
    _Pragma("unroll")                                                          \
    for (int qq = 0; qq < 2; ++qq)                                             \
      _Pragma("unroll")                                                        \
      for (int i = 0; i < 4; ++i) s[qq][i] = (f32x4){0.f, 0.f, 0.f, 0.f};      \
    _Pragma("unroll")                                                          \
    for (int kk = 0; kk < 2; ++kk) {                                           \
      _Pragma("unroll")                                                        \
      for (int i = 0; i < 4; ++i) {                                            \
        short8 ak = *(const short8*)(&Ks[CUR][0] + (i * 16 + l16) * 64 +       \
                                     (((kk * 4 + quad) ^ sw) * 8));            \
        s[0][i] = __builtin_amdgcn_mfma_f32_16x16x32_bf16(ak, aq[0][kk], s[0][i], 0, 0, 0); \
        s[1][i] = __builtin_amdgcn_mfma_f32_16x16x32_bf16(ak, aq[1][kk], s[1][i], 0, 0, 0); \
      }                                                                        \
    }                                                                          \
    union { short8 v; bf16 b[8]; } af[2][2];                                   \
    _Pragma("unroll")                                                          \
    for (int qq = 0; qq < 2; ++qq) {                                           \
      float pe[4][4];                                                          \
      _Pragma("unroll")                                                        \
      for (int i = 0; i < 4; ++i) {                                            \
        _Pragma("unroll")                                                      \
        for (int r = 0; r < 4; ++r) {                                          \
          pe[i][r] = fast_exp2(s[qq][i][r]);                                   \
          if (qq == 0) lp0 += pe[i][r]; else lp1 += pe[i][r];                  \
        }                                                                      \
      }                                                                        \
      _Pragma("unroll")                                                        \
      for (int r = 0; r < 4; ++r) {                                            \
        af[qq][0].b[r]     = fastbf(pe[0][r]);                                 \
        af[qq][0].b[4 + r] = fastbf(pe[1][r]);                                 \
        af[qq][1].b[r]     = fastbf(pe[2][r]);                                 \
        af[qq][1].b[4 + r] = fastbf(pe[3][r]);                                 \
      }                                                                        \
    }                                                                          \
    _Pragma("unroll")                                                          \
    for (int kk = 0; kk < 2; ++kk) {                                           \
      const int g0 = ((4 * kk + (quad >> 1)) ^ sw) * 8 + vh;                   \
      const int g1 = ((4 * kk + 2 + (quad >> 1)) ^ sw) * 8 + vh;               \
      _Pragma("unroll")                                                        \
      for (int dj = 0; dj < 4; ++dj) {                                         \
        const bf16* vrow = &Vs[CUR][0] + (dj * 16 + l16) * 64;                 \
        union { short8 v; uint2 u[2]; } bv;                                    \
        bv.u[0] = *(const uint2*)(vrow + g0);                                  \
        bv.u[1] = *(const uint2*)(vrow + g1);                                  \
        oacc[0][dj] = __builtin_amdgcn_mfma_f32_16x16x32_bf16(af[0][kk].v, bv.v, oacc[0][dj], 0, 0, 0); \
        oacc[1][dj] = __builtin_amdgcn_mfma_f32_16x16x32_bf16(af[1][kk].v, bv.v, oacc[1][dj], 0, 0, 0); \
      }                                                                        \
    }                                                                          \
  }

  for (int c = 0; c < 16; c += 2) {
    ATTN_STEP(0, true)
    ATTN_STEP(1, (c < 14))
  }
#undef ATTN_STEP

  const int b = bh / H_, hh = bh - b * H_;
#pragma unroll
  for (int qq = 0; qq < 2; ++qq) {
    float lt = (qq == 0) ? lp0 : lp1;
    lt += __shfl_xor(lt, 16, 64);
    lt += __shfl_xor(lt, 32, 64);     // lane now holds full sum for q-row l16
#pragma unroll
    for (int r = 0; r < 4; ++r) {
      const float inv = 1.0f / __shfl(lt, quad * 4 + r, 64);
      const int sg = qt * 128 + qq * 64 + wave * 16 + quad * 4 + r;
      const long rowoff = ((long)b * S_ + sg) * D_ + hh * HD_;
#pragma unroll
      for (int dj = 0; dj < 4; ++dj)
        o[rowoff + dj * 16 + l16] = __float2bfloat16(oacc[qq][dj][r] * inv);
    }
  }
}

// ---------------------------------------------------------------------------
extern "C" void kernel_launch(void* const* d_in, const int* in_sizes, int n_in,
                              void* d_out, int out_size, void* d_ws, size_t ws_size,
                              hipStream_t stream) {
  const float* x     = (const float*)d_in[0];
  const float* w_qkv = (const float*)d_in[1];
  const float* w_out = (const float*)d_in[2];
  const float* b_out = (const float*)d_in[3];
  const float* w1    = (const float*)d_in[4];
  const float* b1    = (const float*)d_in[5];
  const float* w2    = (const float*)d_in[6];
  const float* b2    = (const float*)d_in[7];
  float* out = (float*)d_out;

  // workspace layout
  bf16* wt_qkv = (bf16*)d_ws;                 // [2304][768]
  bf16* wt_out = wt_qkv + 2304 * 768;         // [768][768]
  bf16* wt1    = wt_out + 768 * 768;          // [3072][768]
  bf16* wt2    = wt1 + 3072 * 768;            // [768][3072]
  bf16* qb     = wt2 + 768 * 3072;            // [B,H,S,HD] = 6291456
  bf16* kb     = qb + 6291456;
  bf16* vtb    = kb + 6291456;                // [B,H,HD,S]
  bf16* ob     = vtb + 6291456;               // attention out [B,S,D] bf16
  float* x1f   = (float*)(ob + 6291456);      // residual-1 fp32 [B,S,D]
  bf16* hb     = (bf16*)(x1f + 6291456);      // xb (bf16 x); later reused as x1b
  float* redp  = (float*)(hb + 6291456);      // (unused slot, kept for layout)
  float* red_x = redp + 1536;                 // 16 raw sums (norm-1, atomics)
  float* red2  = red_x + 16;                  // 16 raw sums (norm-2, atomics)
  float* cs1   = red2 + 16;                   // colsum(w1)[3072]
  float* csq   = cs1 + 3072;                  // colsum(w_qkv)[2304]
  bf16* gb     = qb;                          // MLP hidden reuses qb..ob (dead)
  bf16* xb     = hb;                          // bf16 cast of x
  bf16* x1b    = hb;                          // bf16 copy of x1 (xb dead after QKV)

  // 1. all weight transposes, 64x64 tiles (+ zero red_x/red2: 32 floats)
  transpose_all<<<1728, 256, 0, stream>>>(w_qkv, w_out, w1, w2,
                                          wt_qkv, wt_out, wt1, wt2, red_x);

  // 2. stats(x) -> red_x (atomics) + bf16 cast -> xb; colsums -> cs1/csq
  stats_partial<<<768 + 48 + 36, 256, 0, stream>>>(x, red_x, wt1, wt_qkv,
                                                   cs1, csq, xb);

  // 3. QKV projection on RAW xb; instance-norm-1 folded into epilogue; scatter
  gemm_k<0, false><<<dim3(64, 18), 256, 0, stream>>>(
      xb, wt_qkv, 8192, 2304, 768, nullptr, nullptr, csq, red_x,
      nullptr, qb, kb, vtb, nullptr);
  // 4. attention (head-major grid; 4 waves, 2 q-tiles = 128 q-rows per block)
  attn64<<<dim3(B_ * H_, 8), 256, 0, stream>>>(qb, kb, vtb, ob);

  // 5. out-projection + bias + residual -> x1f fp32 + x1b bf16, stats -> red2
  gemm_k<1, true><<<dim3(64, 6), 256, 0, stream>>>(
      ob, wt_out, 8192, 768, 768, b_out, x, nullptr, nullptr,
      x1f, x1b, nullptr, nullptr, red2);

  // 6. MLP up on UNNORMALIZED x1b; instance-norm-2 folded; tanh-GELU -> gb
  gemm_k<2, false><<<dim3(64, 24), 256, 0, stream>>>(
      x1b, wt1, 8192, 3072, 768, b1, nullptr, cs1, red2,
      nullptr, gb, nullptr, nullptr, nullptr);

  // 7. MLP down + bias + residual -> out
  gemm_k<3, false><<<dim3(64, 6), 256, 0, stream>>>(
      gb, wt2, 8192, 768, 3072, b2, x1f, nullptr, nullptr,
      out, nullptr, nullptr, nullptr, nullptr);
}